// Round 3
// baseline (271.925 us; speedup 1.0000x reference)
//
#include <hip/hip_runtime.h>

#define NTOK 262144L

typedef __attribute__((ext_vector_type(4))) float f32x4;
typedef __attribute__((ext_vector_type(8))) short bf16x8;   // 8 x bf16 (4 VGPRs)

static __device__ __forceinline__ unsigned short f2bf(float f) {
  unsigned int u = __builtin_bit_cast(unsigned int, f);
  u += 0x7fffu + ((u >> 16) & 1u);          // round-nearest-even
  return (unsigned short)(u >> 16);
}

// ---- pre-pack all weights fp32 -> bf16 in MFMA B-fragment order ----
// W1 region: [e][kt=16][ct=8][lane=64][j=8]  (k = kt*32 + (lane>>4)*8 + j, col = ct*16 + (lane&15))
// W2 region: [e][kt=4 ][ct=8][lane=64][j=8]
__global__ void pack_w(const float* __restrict__ Wt1, const float* __restrict__ Wa1,
                       const float* __restrict__ Wv1, const float* __restrict__ Wt2,
                       const float* __restrict__ Wa2, const float* __restrict__ Wv2,
                       unsigned short* __restrict__ pk) {
  int idx = blockIdx.x * 256 + threadIdx.x;
  if (idx >= 245760) return;
  float v;
  if (idx < 196608) {
    int j = idx & 7, l = (idx >> 3) & 63, ct = (idx >> 9) & 7, kt = (idx >> 12) & 15, e = idx >> 16;
    const float* W = (e == 0) ? Wt1 : (e == 1) ? Wa1 : Wv1;
    v = W[(kt * 32 + ((l >> 4) * 8) + j) * 128 + ct * 16 + (l & 15)];
  } else {
    int i2 = idx - 196608;
    int j = i2 & 7, l = (i2 >> 3) & 63, ct = (i2 >> 9) & 7, kt = (i2 >> 12) & 3, e = i2 >> 14;
    const float* W = (e == 0) ? Wt2 : (e == 1) ? Wa2 : Wv2;
    v = W[(kt * 32 + ((l >> 4) * 8) + j) * 128 + ct * 16 + (l & 15)];
  }
  pk[idx] = f2bf(v);
}

// 32-row x 128-col block, 256 threads (4 waves x 32 cols), 4 blocks/CU.
// Xs swizzle: byte ^= (row&7)<<4
// Hs swizzle: byte ^= ((row&7)<<4) ^ ((row&8)<<2)

__global__ __launch_bounds__(256, 4) void mlp3(
    const float* __restrict__ X, const unsigned short* __restrict__ pk,
    const float* __restrict__ bt1, const float* __restrict__ bt2,
    const float* __restrict__ ba1, const float* __restrict__ ba2,
    const float* __restrict__ bv1, const float* __restrict__ bv2,
    float* __restrict__ out) {
  __shared__ unsigned short Xs[2 * 32 * 128];   // 16 KiB: dbuf 32x128 bf16 X chunk
  __shared__ unsigned short H0[32 * 128];       // 8 KiB
  __shared__ unsigned short H1[32 * 128];       // 8 KiB
  const int t = threadIdx.x;
  const long brow = (long)blockIdx.x * 32;
  const int lane = t & 63;
  const int w = t >> 6;          // wave 0..3 -> cols w*32 .. w*32+31 (ct = 2w, 2w+1)
  const int l15 = lane & 15;
  const int g = lane >> 4;

  const float4* __restrict__ Xv = (const float4*)(X + brow * 512);

  // ---- layer-1 accumulators, all 3 experts ----
  f32x4 at[2][2], aa[2][2], av[2][2];
  #pragma unroll
  for (int c = 0; c < 2; ++c) {
    float b0 = bt1[(2 * w + c) * 16 + l15];
    float b1v = ba1[(2 * w + c) * 16 + l15];
    float b2v = bv1[(2 * w + c) * 16 + l15];
    #pragma unroll
    for (int rt = 0; rt < 2; ++rt) {
      at[rt][c] = (f32x4){b0, b0, b0, b0};
      aa[rt][c] = (f32x4){b1v, b1v, b1v, b1v};
      av[rt][c] = (f32x4){b2v, b2v, b2v, b2v};
    }
  }

  // ---- stage chunk 0 (32 rows x 128 cols) ----
  {
    float4 ld[4];
    #pragma unroll
    for (int i = 0; i < 4; ++i) {
      int f = t + 256 * i;
      ld[i] = Xv[(f >> 5) * 128 + (f & 31)];
    }
    #pragma unroll
    for (int i = 0; i < 4; ++i) {
      int f = t + 256 * i;
      int row = f >> 5, c4 = f & 31;
      unsigned long long p = (unsigned long long)f2bf(ld[i].x)
                           | ((unsigned long long)f2bf(ld[i].y) << 16)
                           | ((unsigned long long)f2bf(ld[i].z) << 32)
                           | ((unsigned long long)f2bf(ld[i].w) << 48);
      int addr = (row * 256 + c4 * 8) ^ ((row & 7) << 4);
      *(unsigned long long*)((char*)Xs + addr) = p;
    }
  }
  __syncthreads();

  unsigned fmask = 0;   // bit rt*4+r: flag != 0 for row rt*16+4g+r

  // ---- fused layer-1 K pipeline: 4 chunks of 128 ----
  #pragma unroll
  for (int kc = 0; kc < 4; ++kc) {
    float4 nx[4];
    if (kc < 3) {   // issue next chunk's loads before the MFMA cluster
      #pragma unroll
      for (int i = 0; i < 4; ++i) {
        int f = t + 256 * i;
        nx[i] = Xv[(f >> 5) * 128 + (kc + 1) * 32 + (f & 31)];
      }
    }
    const char* xb = (const char*)Xs + (kc & 1) * 8192;
    #pragma unroll
    for (int ktl = 0; ktl < 4; ++ktl) {
      int kt = kc * 4 + ktl;
      int wo0 = ((kt * 8 + 2 * w) << 9) + (lane << 3);
      bf16x8 wt0 = *(const bf16x8*)(pk + wo0);
      bf16x8 wt1v = *(const bf16x8*)(pk + wo0 + 512);
      bf16x8 wa0 = *(const bf16x8*)(pk + 65536 + wo0);
      bf16x8 wa1v = *(const bf16x8*)(pk + 65536 + wo0 + 512);
      bf16x8 wv0 = *(const bf16x8*)(pk + 131072 + wo0);
      bf16x8 wv1v = *(const bf16x8*)(pk + 131072 + wo0 + 512);
      #pragma unroll
      for (int rt = 0; rt < 2; ++rt) {
        int row = rt * 16 + l15;
        bf16x8 a = *(const bf16x8*)(xb + ((row * 256 + ktl * 64 + g * 16) ^ ((row & 7) << 4)));
        at[rt][0] = __builtin_amdgcn_mfma_f32_16x16x32_bf16(a, wt0, at[rt][0], 0, 0, 0);
        at[rt][1] = __builtin_amdgcn_mfma_f32_16x16x32_bf16(a, wt1v, at[rt][1], 0, 0, 0);
        aa[rt][0] = __builtin_amdgcn_mfma_f32_16x16x32_bf16(a, wa0, aa[rt][0], 0, 0, 0);
        aa[rt][1] = __builtin_amdgcn_mfma_f32_16x16x32_bf16(a, wa1v, aa[rt][1], 0, 0, 0);
        av[rt][0] = __builtin_amdgcn_mfma_f32_16x16x32_bf16(a, wv0, av[rt][0], 0, 0, 0);
        av[rt][1] = __builtin_amdgcn_mfma_f32_16x16x32_bf16(a, wv1v, av[rt][1], 0, 0, 0);
      }
    }
    if (kc == 3) {
      // routing flags: global col 511 = chunk-3 local col 127 (byte 254), buffer 1
      #pragma unroll
      for (int rt = 0; rt < 2; ++rt)
        #pragma unroll
        for (int r = 0; r < 4; ++r) {
          int row = rt * 16 + 4 * g + r;
          unsigned short fv = *(const unsigned short*)((const char*)Xs + 8192 +
                               ((row * 256 + 254) ^ ((row & 7) << 4)));
          if (fv != 0) fmask |= 1u << (rt * 4 + r);
        }
    }
    if (kc < 3) {
      #pragma unroll
      for (int i = 0; i < 4; ++i) {
        int f = t + 256 * i;
        int row = f >> 5, c4 = f & 31;
        unsigned long long p = (unsigned long long)f2bf(nx[i].x)
                             | ((unsigned long long)f2bf(nx[i].y) << 16)
                             | ((unsigned long long)f2bf(nx[i].z) << 32)
                             | ((unsigned long long)f2bf(nx[i].w) << 48);
        int addr = (((kc + 1) & 1) * 8192) + ((row * 256 + c4 * 8) ^ ((row & 7) << 4));
        *(unsigned long long*)((char*)Xs + addr) = p;
      }
      __syncthreads();
    }
  }

  // ---- relu + write hidden tiles t -> H0, a -> H1 ----
  #pragma unroll
  for (int rt = 0; rt < 2; ++rt)
    #pragma unroll
    for (int c = 0; c < 2; ++c)
      #pragma unroll
      for (int r = 0; r < 4; ++r) {
        int row = rt * 16 + 4 * g + r;
        int col = (2 * w + c) * 16 + l15;
        int ha = (row * 256 + col * 2) ^ ((row & 7) << 4) ^ ((row & 8) << 2);
        *(unsigned short*)((char*)H0 + ha) = f2bf(fmaxf(at[rt][c][r], 0.f));
        *(unsigned short*)((char*)H1 + ha) = f2bf(fmaxf(aa[rt][c][r], 0.f));
      }
  __syncthreads();

  // ---- layer 2 ----
  auto layer2 = [&](const unsigned short* Hb, int e, const float* __restrict__ b2, f32x4 a2[2][2]) {
    #pragma unroll
    for (int c = 0; c < 2; ++c) {
      float bv = b2[(2 * w + c) * 16 + l15];
      a2[0][c] = (f32x4){bv, bv, bv, bv};
      a2[1][c] = (f32x4){bv, bv, bv, bv};
    }
    const unsigned short* W2f = pk + 196608 + e * 16384;
    #pragma unroll
    for (int kt = 0; kt < 4; ++kt) {
      int wo = ((kt * 8 + 2 * w) << 9) + (lane << 3);
      bf16x8 w0 = *(const bf16x8*)(W2f + wo);
      bf16x8 w1 = *(const bf16x8*)(W2f + wo + 512);
      #pragma unroll
      for (int rt = 0; rt < 2; ++rt) {
        int row = rt * 16 + l15;
        bf16x8 a = *(const bf16x8*)((const char*)Hb +
                     ((row * 256 + kt * 64 + g * 16) ^ ((row & 7) << 4) ^ ((row & 8) << 2)));
        a2[rt][0] = __builtin_amdgcn_mfma_f32_16x16x32_bf16(a, w0, a2[rt][0], 0, 0, 0);
        a2[rt][1] = __builtin_amdgcn_mfma_f32_16x16x32_bf16(a, w1, a2[rt][1], 0, 0, 0);
      }
    }
  };

  f32x4 keep[2][2], a2[2][2];
  layer2(H0, 0, bt2, keep);    // transform
  layer2(H1, 1, ba2, a2);      // actor
  #pragma unroll
  for (int rt = 0; rt < 2; ++rt)
    #pragma unroll
    for (int c = 0; c < 2; ++c)
      #pragma unroll
      for (int r = 0; r < 4; ++r)
        if ((fmask >> (rt * 4 + r)) & 1u) keep[rt][c][r] = a2[rt][c][r];
  __syncthreads();             // all L2-t/L2-a reads done -> H0 reusable

  // ---- value head hidden + layer 2 ----
  #pragma unroll
  for (int rt = 0; rt < 2; ++rt)
    #pragma unroll
    for (int c = 0; c < 2; ++c)
      #pragma unroll
      for (int r = 0; r < 4; ++r) {
        int row = rt * 16 + 4 * g + r;
        int col = (2 * w + c) * 16 + l15;
        int ha = (row * 256 + col * 2) ^ ((row & 7) << 4) ^ ((row & 8) << 2);
        *(unsigned short*)((char*)H0 + ha) = f2bf(fmaxf(av[rt][c][r], 0.f));
      }
  __syncthreads();
  layer2(H0, 2, bv2, a2);      // value

  // ---- batched stores ----
  float* __restrict__ ov = out + NTOK * 128;
  #pragma unroll
  for (int rt = 0; rt < 2; ++rt)
    #pragma unroll
    for (int c = 0; c < 2; ++c)
      #pragma unroll
      for (int r = 0; r < 4; ++r) {
        long row = brow + rt * 16 + 4 * g + r;
        long col = (2 * w + c) * 16 + l15;
        out[row * 128 + col] = keep[rt][c][r];
        ov[row * 128 + col] = fmaxf(a2[rt][c][r], 0.f);
      }
}

extern "C" void kernel_launch(void* const* d_in, const int* in_sizes, int n_in,
                              void* d_out, int out_size, void* d_ws, size_t ws_size,
                              hipStream_t stream) {
  const float* X   = (const float*)d_in[0];
  const float* Wt1 = (const float*)d_in[1];
  const float* bt1 = (const float*)d_in[2];
  const float* Wt2 = (const float*)d_in[3];
  const float* bt2 = (const float*)d_in[4];
  const float* Wa1 = (const float*)d_in[5];
  const float* ba1 = (const float*)d_in[6];
  const float* Wa2 = (const float*)d_in[7];
  const float* ba2 = (const float*)d_in[8];
  const float* Wv1 = (const float*)d_in[9];
  const float* bv1 = (const float*)d_in[10];
  const float* Wv2 = (const float*)d_in[11];
  const float* bv2 = (const float*)d_in[12];
  unsigned short* pk = (unsigned short*)d_ws;   // 245760 bf16 = 480 KiB packed weights

  pack_w<<<960, 256, 0, stream>>>(Wt1, Wa1, Wv1, Wt2, Wa2, Wv2, pk);
  mlp3<<<8192, 256, 0, stream>>>(X, pk, bt1, bt2, ba1, ba2, bv1, bv2, (float*)d_out);
}

// Round 4
// 264.231 us; speedup vs baseline: 1.0291x; 1.0291x over previous
//
#include <hip/hip_runtime.h>

#define NTOK 262144L

typedef __attribute__((ext_vector_type(4))) float f32x4;
typedef __attribute__((ext_vector_type(8))) short bf16x8;   // 8 x bf16 (4 VGPRs)

static __device__ __forceinline__ unsigned short f2bf(float f) {
  unsigned int u = __builtin_bit_cast(unsigned int, f);
  u += 0x7fffu + ((u >> 16) & 1u);          // round-nearest-even
  return (unsigned short)(u >> 16);
}

static __device__ __forceinline__ unsigned cvtpk(float lo, float hi) {
  unsigned r;
  asm("v_cvt_pk_bf16_f32 %0, %1, %2" : "=v"(r) : "v"(lo), "v"(hi));
  return r;
}

union U8 { unsigned u[4]; bf16x8 v; };

// async global->LDS, 16B per lane; dest is wave-uniform base (HW adds lane*16)
static __device__ __forceinline__ void dma16(const float* gsrc, void* ldst) {
  __builtin_amdgcn_global_load_lds(
      (const __attribute__((address_space(1))) unsigned int*)gsrc,
      (__attribute__((address_space(3))) unsigned int*)ldst, 16, 0, 0);
}

// X (fp32, 512B rows = 32 x 16B slots): slot = c16 ^ sigx(row) -> A-frag reads 2-way max
static __device__ __forceinline__ int sigx(int row) {
  return (row & 1) | ((row & 8) >> 2) | ((row & 6) << 2);
}
// H (bf16, 256B rows = 16 x 16B slots): byte-XOR key
static __device__ __forceinline__ int swzh(int row) {
  return ((row & 8) << 1) | ((row & 6) << 5);
}

// ---- pre-pack all weights fp32 -> bf16 in MFMA B-fragment order ----
// W1 region: [e][kt=16][ct=8][lane=64][j=8]  (k = kt*32 + (lane>>4)*8 + j, col = ct*16 + (lane&15))
// W2 region: [e][kt=4 ][ct=8][lane=64][j=8]
__global__ void pack_w(const float* __restrict__ Wt1, const float* __restrict__ Wa1,
                       const float* __restrict__ Wv1, const float* __restrict__ Wt2,
                       const float* __restrict__ Wa2, const float* __restrict__ Wv2,
                       unsigned short* __restrict__ pk) {
  int idx = blockIdx.x * 256 + threadIdx.x;
  if (idx >= 245760) return;
  float v;
  if (idx < 196608) {
    int j = idx & 7, l = (idx >> 3) & 63, ct = (idx >> 9) & 7, kt = (idx >> 12) & 15, e = idx >> 16;
    const float* W = (e == 0) ? Wt1 : (e == 1) ? Wa1 : Wv1;
    v = W[(kt * 32 + ((l >> 4) * 8) + j) * 128 + ct * 16 + (l & 15)];
  } else {
    int i2 = idx - 196608;
    int j = i2 & 7, l = (i2 >> 3) & 63, ct = (i2 >> 9) & 7, kt = (i2 >> 12) & 3, e = i2 >> 14;
    const float* W = (e == 0) ? Wt2 : (e == 1) ? Wa2 : Wv2;
    v = W[(kt * 32 + ((l >> 4) * 8) + j) * 128 + ct * 16 + (l & 15)];
  }
  pk[idx] = f2bf(v);
}

// load A-frag (8 floats @ k = ktl*32 + g*8) from swizzled fp32 LDS, convert to bf16x8
static __device__ __forceinline__ bf16x8 ldA(const char* xb, int row, int ktl, int g) {
  int swz = sigx(row) << 4;
  int base = row * 512 + ktl * 128 + g * 32;
  f32x4 f0 = *(const f32x4*)(xb + (base ^ swz));
  f32x4 f1 = *(const f32x4*)(xb + ((base + 16) ^ swz));
  U8 r;
  r.u[0] = cvtpk(f0[0], f0[1]);
  r.u[1] = cvtpk(f0[2], f0[3]);
  r.u[2] = cvtpk(f1[0], f1[1]);
  r.u[3] = cvtpk(f1[2], f1[3]);
  return r.v;
}

// store relu(acc) (4 rows 4g..4g+3, one col) into swizzled bf16 H tile
static __device__ __forceinline__ void stH(char* Hb, int g, int col, int rbase, f32x4 a) {
  #pragma unroll
  for (int rp = 0; rp < 2; ++rp) {
    int r0 = rbase + 4 * g + 2 * rp;
    unsigned p = cvtpk(fmaxf(a[2 * rp], 0.f), fmaxf(a[2 * rp + 1], 0.f));
    int a0 = r0 * 256 + ((((col >> 3) << 4)) ^ swzh(r0)) + (col & 7) * 2;
    int a1 = (r0 + 1) * 256 + ((((col >> 3) << 4)) ^ swzh(r0 + 1)) + (col & 7) * 2;
    *(unsigned short*)(Hb + a0) = (unsigned short)p;
    *(unsigned short*)(Hb + a1) = (unsigned short)(p >> 16);
  }
}

static __device__ __forceinline__ bf16x8 ldH(const char* hb, int row, int kt, int g) {
  return *(const bf16x8*)(hb + row * 256 + ((((kt * 4 + g) << 4)) ^ swzh(row)));
}

__global__ __launch_bounds__(256, 4) void mlp3(
    const float* __restrict__ X, const unsigned short* __restrict__ pk,
    const float* __restrict__ bt1, const float* __restrict__ bt2,
    const float* __restrict__ ba1, const float* __restrict__ ba2,
    const float* __restrict__ bv1, const float* __restrict__ bv2,
    float* __restrict__ out) {
  __shared__ float Xs[2 * 32 * 128];            // 32 KiB: dbuf 32x128 fp32 X chunk (DMA target)
  __shared__ unsigned short H0[32 * 128];       // 8 KiB
  __shared__ unsigned short H1[32 * 128];       // 8 KiB
  const int t = threadIdx.x;
  const long brow = (long)blockIdx.x * 32;
  const int lane = t & 63;
  const int w = t >> 6;          // wave 0..3 -> cols w*32 .. w*32+31 (ct = 2w, 2w+1)
  const int l15 = lane & 15;
  const int g = lane >> 4;

  const float* __restrict__ Xrow = X + brow * 512;

  // ---- layer-1 accumulators, all 3 experts ----
  f32x4 at[2][2], aa[2][2], av[2][2];
  #pragma unroll
  for (int c = 0; c < 2; ++c) {
    float b0 = bt1[(2 * w + c) * 16 + l15];
    float b1v = ba1[(2 * w + c) * 16 + l15];
    float b2v = bv1[(2 * w + c) * 16 + l15];
    #pragma unroll
    for (int rt = 0; rt < 2; ++rt) {
      at[rt][c] = (f32x4){b0, b0, b0, b0};
      aa[rt][c] = (f32x4){b1v, b1v, b1v, b1v};
      av[rt][c] = (f32x4){b2v, b2v, b2v, b2v};
    }
  }

  // ---- DMA chunk 0 (inverse-swizzled source, linear LDS dest) ----
  #pragma unroll
  for (int i = 0; i < 4; ++i) {
    int lin = i * 256 + t;
    int row = lin >> 5, S = lin & 31;
    dma16(Xrow + row * 512 + ((S ^ sigx(row)) << 2),
          (char*)Xs + i * 4096 + w * 1024);
  }
  __syncthreads();

  unsigned fmask = 0;   // bit rt*4+r: flag != 0 for row rt*16+4g+r

  // ---- fused layer-1 K pipeline: 4 chunks of 128 ----
  #pragma unroll
  for (int kc = 0; kc < 4; ++kc) {
    if (kc < 3) {   // async-issue next chunk before this chunk's MFMA cluster
      #pragma unroll
      for (int i = 0; i < 4; ++i) {
        int lin = i * 256 + t;
        int row = lin >> 5, S = lin & 31;
        dma16(Xrow + row * 512 + (kc + 1) * 128 + ((S ^ sigx(row)) << 2),
              (char*)Xs + ((kc + 1) & 1) * 16384 + i * 4096 + w * 1024);
      }
    }
    const char* xb = (const char*)Xs + (kc & 1) * 16384;
    __builtin_amdgcn_s_setprio(1);
    #pragma unroll
    for (int ktl = 0; ktl < 4; ++ktl) {
      int kt = kc * 4 + ktl;
      int wo0 = ((kt * 8 + 2 * w) << 9) + (lane << 3);
      bf16x8 wt0 = *(const bf16x8*)(pk + wo0);
      bf16x8 wt1v = *(const bf16x8*)(pk + wo0 + 512);
      bf16x8 wa0 = *(const bf16x8*)(pk + 65536 + wo0);
      bf16x8 wa1v = *(const bf16x8*)(pk + 65536 + wo0 + 512);
      bf16x8 wv0 = *(const bf16x8*)(pk + 131072 + wo0);
      bf16x8 wv1v = *(const bf16x8*)(pk + 131072 + wo0 + 512);
      #pragma unroll
      for (int rt = 0; rt < 2; ++rt) {
        bf16x8 a = ldA(xb, rt * 16 + l15, ktl, g);
        at[rt][0] = __builtin_amdgcn_mfma_f32_16x16x32_bf16(a, wt0, at[rt][0], 0, 0, 0);
        at[rt][1] = __builtin_amdgcn_mfma_f32_16x16x32_bf16(a, wt1v, at[rt][1], 0, 0, 0);
        aa[rt][0] = __builtin_amdgcn_mfma_f32_16x16x32_bf16(a, wa0, aa[rt][0], 0, 0, 0);
        aa[rt][1] = __builtin_amdgcn_mfma_f32_16x16x32_bf16(a, wa1v, aa[rt][1], 0, 0, 0);
        av[rt][0] = __builtin_amdgcn_mfma_f32_16x16x32_bf16(a, wv0, av[rt][0], 0, 0, 0);
        av[rt][1] = __builtin_amdgcn_mfma_f32_16x16x32_bf16(a, wv1v, av[rt][1], 0, 0, 0);
      }
    }
    __builtin_amdgcn_s_setprio(0);
    if (kc == 3) {
      // routing flags: global col 511 -> chunk-3 local float col 127 (c16=31, byte 12), buf 1
      #pragma unroll
      for (int rt = 0; rt < 2; ++rt)
        #pragma unroll
        for (int r = 0; r < 4; ++r) {
          int row = rt * 16 + 4 * g + r;
          float fv = *(const float*)(xb + row * 512 + (((31 ^ sigx(row)) << 4)) + 12);
          if (fv != 0.f) fmask |= 1u << (rt * 4 + r);
        }
    }
    if (kc < 3) __syncthreads();   // drains DMA (chunk kc+1 ready) + guards buf reuse
  }

  // ---- relu + write hidden tiles t -> H0, a -> H1 ----
  #pragma unroll
  for (int rt = 0; rt < 2; ++rt)
    #pragma unroll
    for (int c = 0; c < 2; ++c) {
      int col = (2 * w + c) * 16 + l15;
      stH((char*)H0, g, col, rt * 16, at[rt][c]);
      stH((char*)H1, g, col, rt * 16, aa[rt][c]);
    }
  __syncthreads();

  // ---- layer 2 ----
  auto layer2 = [&](const unsigned short* Hb, int e, const float* __restrict__ b2, f32x4 a2[2][2]) {
    #pragma unroll
    for (int c = 0; c < 2; ++c) {
      float bv = b2[(2 * w + c) * 16 + l15];
      a2[0][c] = (f32x4){bv, bv, bv, bv};
      a2[1][c] = (f32x4){bv, bv, bv, bv};
    }
    const unsigned short* W2f = pk + 196608 + e * 16384;
    __builtin_amdgcn_s_setprio(1);
    #pragma unroll
    for (int kt = 0; kt < 4; ++kt) {
      int wo = ((kt * 8 + 2 * w) << 9) + (lane << 3);
      bf16x8 w0 = *(const bf16x8*)(W2f + wo);
      bf16x8 w1 = *(const bf16x8*)(W2f + wo + 512);
      #pragma unroll
      for (int rt = 0; rt < 2; ++rt) {
        bf16x8 a = ldH((const char*)Hb, rt * 16 + l15, kt, g);
        a2[rt][0] = __builtin_amdgcn_mfma_f32_16x16x32_bf16(a, w0, a2[rt][0], 0, 0, 0);
        a2[rt][1] = __builtin_amdgcn_mfma_f32_16x16x32_bf16(a, w1, a2[rt][1], 0, 0, 0);
      }
    }
    __builtin_amdgcn_s_setprio(0);
  };

  f32x4 keep[2][2], a2[2][2];
  layer2(H0, 0, bt2, keep);    // transform
  layer2(H1, 1, ba2, a2);      // actor
  #pragma unroll
  for (int rt = 0; rt < 2; ++rt)
    #pragma unroll
    for (int c = 0; c < 2; ++c)
      #pragma unroll
      for (int r = 0; r < 4; ++r)
        if ((fmask >> (rt * 4 + r)) & 1u) keep[rt][c][r] = a2[rt][c][r];
  __syncthreads();             // all layer-2 t/a reads done -> H0 reusable

  // ---- value head hidden + layer 2 ----
  #pragma unroll
  for (int rt = 0; rt < 2; ++rt)
    #pragma unroll
    for (int c = 0; c < 2; ++c) {
      int col = (2 * w + c) * 16 + l15;
      stH((char*)H0, g, col, rt * 16, av[rt][c]);
    }
  __syncthreads();
  layer2(H0, 2, bv2, a2);      // value

  // ---- batched stores ----
  float* __restrict__ ov = out + NTOK * 128;
  #pragma unroll
  for (int rt = 0; rt < 2; ++rt)
    #pragma unroll
    for (int c = 0; c < 2; ++c)
      #pragma unroll
      for (int r = 0; r < 4; ++r) {
        long row = brow + rt * 16 + 4 * g + r;
        long col = (2 * w + c) * 16 + l15;
        out[row * 128 + col] = keep[rt][c][r];
        ov[row * 128 + col] = fmaxf(a2[rt][c][r], 0.f);
      }
}

extern "C" void kernel_launch(void* const* d_in, const int* in_sizes, int n_in,
                              void* d_out, int out_size, void* d_ws, size_t ws_size,
                              hipStream_t stream) {
  const float* X   = (const float*)d_in[0];
  const float* Wt1 = (const float*)d_in[1];
  const float* bt1 = (const float*)d_in[2];
  const float* Wt2 = (const float*)d_in[3];
  const float* bt2 = (const float*)d_in[4];
  const float* Wa1 = (const float*)d_in[5];
  const float* ba1 = (const float*)d_in[6];
  const float* Wa2 = (const float*)d_in[7];
  const float* ba2 = (const float*)d_in[8];
  const float* Wv1 = (const float*)d_in[9];
  const float* bv1 = (const float*)d_in[10];
  const float* Wv2 = (const float*)d_in[11];
  const float* bv2 = (const float*)d_in[12];
  unsigned short* pk = (unsigned short*)d_ws;   // 245760 bf16 = 480 KiB packed weights

  pack_w<<<960, 256, 0, stream>>>(Wt1, Wa1, Wv1, Wt2, Wa2, Wv2, pk);
  mlp3<<<8192, 256, 0, stream>>>(X, pk, bt1, bt2, ba1, ba2, bv1, bv2, (float*)d_out);
}